// Round 11
// baseline (121.119 us; speedup 1.0000x reference)
//
#include <hip/hip_runtime.h>
#include <math.h>

// Problem constants (match reference)
#define N_ATOMS 256
#define N_FEAT  128
#define BATCH   8
#define BINS    300
#define INV_STEP 149.5f        // 1/STEP, STEP = 2/(BINS-1)
#define ONE_OVER_2PI 0.15915494309189535f
#define INV_112 0.8928571428571429f   // 1/1.12
#define WIN 2                  // bins beyond |d|=2 contribute < exp(-9)*|basis| ~ 1e-5 << tol
#define WINW 5                 // 2*WIN+1
#define NHIST 4                // privatized histogram copies per node

struct V3 { float x, y, z; };
__device__ __forceinline__ V3 v3sub(V3 a, V3 b) { return {a.x-b.x, a.y-b.y, a.z-b.z}; }
__device__ __forceinline__ float v3dot(V3 a, V3 b) { return a.x*b.x + a.y*b.y + a.z*b.z; }
__device__ __forceinline__ V3 v3cross(V3 a, V3 b) {
    return {a.y*b.z - a.z*b.y, a.z*b.x - a.x*b.z, a.x*b.y - a.y*b.x};
}
__device__ __forceinline__ V3 v3nrm(V3 a) {
    float r = __builtin_amdgcn_rsqf(v3dot(a, a));   // v_rsq_f32
    return {a.x*r, a.y*r, a.z*r};
}
__device__ __forceinline__ float clamp1(float x) { return fminf(1.0f, fmaxf(-1.0f, x)); }

// Branchless Cephes asinf: |x|<=0.5 poly; else pi/2 - 2*asin(sqrt((1-|x|)/2)).
__device__ __forceinline__ float asin_fast(float x) {
    float u = fabsf(x);
    bool big = u > 0.5f;
    float z = big ? 0.5f * (1.0f - u) : u * u;
    float s = big ? __builtin_amdgcn_sqrtf(z) : u;  // v_sqrt_f32
    float p = fmaf(z, 4.2163199048e-2f, 2.4181311049e-2f);
    p = fmaf(z, p, 4.5470025998e-2f);
    p = fmaf(z, p, 7.4953002686e-2f);
    p = fmaf(z, p, 1.6666752422e-1f);
    float r = fmaf(s * z, p, s);
    r = big ? (1.5707963267948966f - 2.0f * r) : r;
    return copysignf(r, x);
}

// writhe of segment pair (i,i+1),(j,j+1) from SoA LDS coords
__device__ __forceinline__ float writhe_ij(const float* cx, const float* cy,
                                           const float* cz, int i, int j) {
    V3 pi  = {cx[i],   cy[i],   cz[i]};
    V3 pi1 = {cx[i+1], cy[i+1], cz[i+1]};
    V3 pj  = {cx[j],   cy[j],   cz[j]};
    V3 pj1 = {cx[j+1], cy[j+1], cz[j+1]};

    V3 d0 = v3nrm(v3sub(pj,  pi));
    V3 d1 = v3nrm(v3sub(pj1, pi));
    V3 d2 = v3nrm(v3sub(pj,  pi1));
    V3 d3 = v3nrm(v3sub(pj1, pi1));

    V3 c0 = v3nrm(v3cross(d0, d1));
    V3 c1 = v3nrm(v3cross(d1, d3));
    V3 c2 = v3nrm(v3cross(d3, d2));
    V3 c3 = v3nrm(v3cross(d2, d0));

    float omega = asin_fast(clamp1(v3dot(c0, c1)))
                + asin_fast(clamp1(v3dot(c1, c2)))
                + asin_fast(clamp1(v3dot(c2, c3)))
                + asin_fast(clamp1(v3dot(c3, c0)));

    float sg = v3dot(v3cross(v3sub(pj1, pj), v3sub(pi1, pi)), d0);
    float sign = (sg > 0.0f) ? 1.0f : ((sg < 0.0f) ? -1.0f : 0.0f);
    return omega * sign * ONE_OVER_2PI;
}

// One 512-thread block per NODE PAIR (t0, t1) = (p+2, 255-p), same batch.
// Edge counts sum to 508 for p>=1 (254 for p=0): one edge per thread.
// Node tau edges: type-1 = segment (a,tau), a in [0,tau-2] (iff tau<=254);
// type-2 = segment (a-1,tau-1), a in [1,tau-2]; weight g = exp(-|c_a-c_tau|^2).
// typ is folded into a single writhe_ij(a-typ, tau-typ) call -> no divergent
// double execution of the ~270-instr writhe body.
__global__ __launch_bounds__(512) void fused_kernel(const float* __restrict__ coords,
                                                    const float* __restrict__ nf,
                                                    const float* __restrict__ basis,
                                                    float* __restrict__ out) {
    const int blk = blockIdx.x;
    const int b = blk & 7;
    const int p = blk >> 3;            // pair index 0..126
    const int t0 = p + 2;              // 2..128
    const int t1 = 255 - p;            // 255..129
    const int tid = threadIdx.x;

    const int E0  = 2 * t0 - 3;                         // edges of node t0
    const int E1n = (t1 == 255) ? 253 : 2 * t1 - 3;     // edges of node t1

    float mynf = 0.0f;
    if (tid < 256) {                   // prefetch nf rows t0 (tid<128) and t1
        const int row = (tid >> 7) ? t1 : t0;
        mynf = nf[((size_t)((b << 8) | row)) * N_FEAT + (tid & 127)];
    }

    __shared__ float csx[N_ATOMS], csy[N_ATOMS], csz[N_ATOMS];  // 3 KB SoA
    __shared__ float h2[2 * NHIST * BINS];   // 9.6 KB (two 4-copy histograms)
    __shared__ float sden[2];
    __shared__ int skmin[2], skmax[2];

    if (tid < N_ATOMS) {
        const int gbase = ((b << 8) + tid) * 3;
        csx[tid] = coords[gbase + 0];
        csy[tid] = coords[gbase + 1];
        csz[tid] = coords[gbase + 2];
    }
    for (int k = tid; k < 2 * NHIST * BINS; k += 512) h2[k] = 0.0f;
    if (tid < 2) { sden[tid] = 0.0f; skmin[tid] = BINS - 1; skmax[tid] = 0; }
    __syncthreads();

    int node = -1;
    int tau = t0;
    if (tid < E0) { node = 0; }
    else if (tid < E0 + E1n) { node = 1; tau = t1; }
    const int ee = (node == 1) ? tid - E0 : tid;

    float d0 = 0.0f, d1 = 0.0f;
    int kn0 = BINS - 1, kx0 = 0, kn1 = BINS - 1, kx1 = 0;

    if (node >= 0) {
        const int eT1 = (tau <= N_ATOMS - 2) ? tau - 1 : 0;
        const int typ = (ee < eT1) ? 0 : 1;
        const int a = (typ == 0) ? ee : ee - eT1 + 1;

        float dx = csx[a] - csx[tau];
        float dy = csy[a] - csy[tau];
        float dz = csz[a] - csz[tau];
        float g = __expf(-(dx*dx + dy*dy + dz*dz));

        // single call, shifted indices: segment (a-typ, tau-typ)
        float w = writhe_ij(csx, csy, csz, a - typ, tau - typ);
        float pp = (w + 1.0f) * INV_STEP;    // pp - k = (w - c_k)/STEP
        int k0 = __float2int_rn(pp);
        int kmn = max(0, k0 - WIN);
        int kmx = min(BINS - 1, k0 + WIN);
        if (node == 0) { d0 = g; kn0 = kmn; kx0 = kmx; }
        else           { d1 = g; kn1 = kmn; kx1 = kmx; }

        const int copy = tid & (NHIST - 1);
        const int rot = tid % WINW;          // (tid&3, tid%5) pairs: <=4-way alias, cheap
        const int base = (node * NHIST + copy) * BINS;
        const int klo = k0 - WIN;
        #pragma unroll
        for (int m = 0; m < WINW; ++m) {
            int mm = m + rot; if (mm >= WINW) mm -= WINW;
            int k = klo + mm;
            if (k >= 0 && k < BINS) {
                float dd = pp - (float)k;
                atomicAdd(&h2[base + k], g * __expf(-dd * dd));
            }
        }
    }

    // per-wave masked butterflies for both nodes, one LDS atomic set per wave
    #pragma unroll
    for (int off = 32; off > 0; off >>= 1) {
        d0 += __shfl_xor(d0, off, 64);
        d1 += __shfl_xor(d1, off, 64);
        kn0 = min(kn0, __shfl_xor(kn0, off, 64));
        kx0 = max(kx0, __shfl_xor(kx0, off, 64));
        kn1 = min(kn1, __shfl_xor(kn1, off, 64));
        kx1 = max(kx1, __shfl_xor(kx1, off, 64));
    }
    if ((tid & 63) == 0) {
        atomicAdd(&sden[0], d0);
        atomicAdd(&sden[1], d1);
        atomicMin(&skmin[0], kn0);
        atomicMax(&skmax[0], kx0);
        atomicMin(&skmin[1], kn1);
        atomicMax(&skmax[1], kx1);
    }
    __syncthreads();

    // combine the 4 privatized copies per node into copy 0, touched range only
    {
        const int nu = tid >> 8;             // 256 threads per node
        const int kmin = skmin[nu], kmax = skmax[nu];
        const int base = nu * NHIST * BINS;
        for (int k = kmin + (tid & 255); k <= kmax; k += 256) {
            float s = h2[base + k] + h2[base + BINS + k]
                    + h2[base + 2 * BINS + k] + h2[base + 3 * BINS + k];
            h2[base + k] = s;
        }
    }
    __syncthreads();

    // projection + direct write: 2 nodes x 128 features on threads 0..255
    if (tid < 256) {
        const int nu = tid >> 7;
        const int f = tid & 127;
        const int kmin = skmin[nu], kmax = skmax[nu];
        const int base = nu * NHIST * BINS;
        float acc = 0.0f;
        for (int k = kmin; k <= kmax; ++k)
            acc = fmaf(h2[base + k], basis[k * N_FEAT + f], acc);
        const int row = nu ? t1 : t0;
        out[((size_t)((b << 8) | row)) * N_FEAT + f] = mynf + acc * (INV_112 / sden[nu]);
    } else if (p == 0) {
        // passthrough rows t = 0, 1 (no incoming edges), from the (2,255) block
        const int tid2 = tid - 256;
        const int r = tid2 >> 7;
        const int f = tid2 & 127;
        const size_t idx = ((size_t)((b << 8) | r)) * N_FEAT + f;
        out[idx] = nf[idx];
    }
}

extern "C" void kernel_launch(void* const* d_in, const int* in_sizes, int n_in,
                              void* d_out, int out_size, void* d_ws, size_t ws_size,
                              hipStream_t stream) {
    const float* coords = (const float*)d_in[0];   // (B*N, 3) f32
    const float* nf     = (const float*)d_in[1];   // (B*N, 128) f32
    const float* basis  = (const float*)d_in[2];   // (300, 128) f32
    float* out = (float*)d_out;                    // (B*N, 128) f32

    fused_kernel<<<BATCH * 127, 512, 0, stream>>>(coords, nf, basis, out);
}

// Round 12
// 118.111 us; speedup vs baseline: 1.0255x; 1.0255x over previous
//
#include <hip/hip_runtime.h>
#include <math.h>

// Problem constants (match reference)
#define N_ATOMS 256
#define N_FEAT  128
#define BATCH   8
#define BINS    300
#define INV_STEP 149.5f        // 1/STEP, STEP = 2/(BINS-1)
#define ONE_OVER_2PI 0.15915494309189535f
#define INV_112 0.8928571428571429f   // 1/1.12
#define WIN 2                  // bins beyond |d|=2 contribute < exp(-9)*|basis| ~ 1e-5 << tol
#define WINW 5                 // 2*WIN+1
#define NHIST 8                // privatized histogram copies per node

struct V3 { float x, y, z; };
__device__ __forceinline__ V3 v3sub(V3 a, V3 b) { return {a.x-b.x, a.y-b.y, a.z-b.z}; }
__device__ __forceinline__ float v3dot(V3 a, V3 b) { return a.x*b.x + a.y*b.y + a.z*b.z; }
__device__ __forceinline__ V3 v3cross(V3 a, V3 b) {
    return {a.y*b.z - a.z*b.y, a.z*b.x - a.x*b.z, a.x*b.y - a.y*b.x};
}
__device__ __forceinline__ V3 v3nrm(V3 a) {
    float r = __builtin_amdgcn_rsqf(v3dot(a, a));   // v_rsq_f32
    return {a.x*r, a.y*r, a.z*r};
}
__device__ __forceinline__ float clamp1(float x) { return fminf(1.0f, fmaxf(-1.0f, x)); }

// Branchless Cephes asinf: |x|<=0.5 poly; else pi/2 - 2*asin(sqrt((1-|x|)/2)).
__device__ __forceinline__ float asin_fast(float x) {
    float u = fabsf(x);
    bool big = u > 0.5f;
    float z = big ? 0.5f * (1.0f - u) : u * u;
    float s = big ? __builtin_amdgcn_sqrtf(z) : u;  // v_sqrt_f32
    float p = fmaf(z, 4.2163199048e-2f, 2.4181311049e-2f);
    p = fmaf(z, p, 4.5470025998e-2f);
    p = fmaf(z, p, 7.4953002686e-2f);
    p = fmaf(z, p, 1.6666752422e-1f);
    float r = fmaf(s * z, p, s);
    r = big ? (1.5707963267948966f - 2.0f * r) : r;
    return copysignf(r, x);
}

// writhe of segment pair (i,i+1),(j,j+1) from AoS LDS coords
__device__ __forceinline__ float writhe_ij(const float* cs, int i, int j) {
    V3 pi  = {cs[i*3+0],     cs[i*3+1],     cs[i*3+2]};
    V3 pi1 = {cs[(i+1)*3+0], cs[(i+1)*3+1], cs[(i+1)*3+2]};
    V3 pj  = {cs[j*3+0],     cs[j*3+1],     cs[j*3+2]};
    V3 pj1 = {cs[(j+1)*3+0], cs[(j+1)*3+1], cs[(j+1)*3+2]};

    V3 d0 = v3nrm(v3sub(pj,  pi));
    V3 d1 = v3nrm(v3sub(pj1, pi));
    V3 d2 = v3nrm(v3sub(pj,  pi1));
    V3 d3 = v3nrm(v3sub(pj1, pi1));

    V3 c0 = v3nrm(v3cross(d0, d1));
    V3 c1 = v3nrm(v3cross(d1, d3));
    V3 c2 = v3nrm(v3cross(d3, d2));
    V3 c3 = v3nrm(v3cross(d2, d0));

    float omega = asin_fast(clamp1(v3dot(c0, c1)))
                + asin_fast(clamp1(v3dot(c1, c2)))
                + asin_fast(clamp1(v3dot(c2, c3)))
                + asin_fast(clamp1(v3dot(c3, c0)));

    float sg = v3dot(v3cross(v3sub(pj1, pj), v3sub(pi1, pi)), d0);
    float sign = (sg > 0.0f) ? 1.0f : ((sg < 0.0f) ? -1.0f : 0.0f);
    return omega * sign * ONE_OVER_2PI;
}

// gaussian edge weight between atoms a and t (AoS LDS)
__device__ __forceinline__ float gw(const float* cs, int a, int t) {
    float dx = cs[a*3+0] - cs[t*3+0];
    float dy = cs[a*3+1] - cs[t*3+1];
    float dz = cs[a*3+2] - cs[t*3+2];
    return __expf(-(dx*dx + dy*dy + dz*dz));
}

// One 512-thread block per CONSECUTIVE node pair (w, w+1), w = 2p+2, p in
// [0,126] (covers nodes 2..255). Segment-family dedup: family F(tau) =
// {writhe(i,tau), i in [0,tau-2]} — F(w) serves BOTH node w (type-1, weight
// g(i,w)) and node w+1 (type-2, weight g(i+1,w+1)); F(w-1) serves node w
// type-2 (g(i+1,w)); F(w+1) serves node w+1 type-1 (g(i,w+1), only if
// w+1<=254). Evals/block = 3w-3 (vs 4w-4 un-deduped = 25% writhe cut).
// Per-CU balance: alternating map p = q&1 ? 126-q/2 : q/2 mixes heavy+light
// blocks on each CU. Grid 1016x512 = 32 waves/CU (round-7 lesson: keep TLP).
__global__ __launch_bounds__(512) void fused_kernel(const float* __restrict__ coords,
                                                    const float* __restrict__ nf,
                                                    const float* __restrict__ basis,
                                                    float* __restrict__ out) {
    const int blk = blockIdx.x;
    const int b = blk & 7;
    const int q = blk >> 3;                         // 0..126
    const int p = (q & 1) ? (126 - (q >> 1)) : (q >> 1);   // bijective, heavy/light interleave
    const int w = 2 * p + 2;                        // nodes (w, w+1), w in 2..254
    const int tid = threadIdx.x;

    const int E0 = w - 2;                           // |F(w-1)|
    const int E1 = w - 1;                           // |F(w)| (shared family)
    const int E2 = (w + 1 <= N_ATOMS - 2) ? w : 0;  // |F(w+1)|, 0 when w+1 == 255
    const int E = E0 + E1 + E2;

    float mynf = 0.0f;
    if (tid < 256) {                                // prefetch nf rows w, w+1
        const int row = w + (tid >> 7);
        mynf = nf[((size_t)((b << 8) | row)) * N_FEAT + (tid & 127)];
    }

    __shared__ float cs[N_ATOMS * 3];               // 3 KB AoS
    __shared__ float h2[2 * NHIST * BINS];          // 19.2 KB (two 8-copy histograms)
    __shared__ float part[4 * N_FEAT];              // 2 KB
    __shared__ float sden[2];
    __shared__ int skmin[2], skmax[2];

    for (int idx = tid; idx < N_ATOMS * 3; idx += 512)
        cs[idx] = coords[(b << 8) * 3 + idx];
    for (int k = tid; k < 2 * NHIST * BINS; k += 512) h2[k] = 0.0f;
    if (tid < 2) { sden[tid] = 0.0f; skmin[tid] = BINS - 1; skmax[tid] = 0; }
    __syncthreads();

    float d0 = 0.0f, d1 = 0.0f;
    int kn0 = BINS - 1, kx0 = 0, kn1 = BINS - 1, kx1 = 0;
    const int copy = tid & (NHIST - 1);
    const int rot = tid % WINW;
    const int baseA0 = copy * BINS;                 // node w histogram, this copy
    const int baseB  = (NHIST + copy) * BINS;       // node w+1 histogram, this copy

    for (int e = tid; e < E; e += 512) {
        int tau, i;
        if (e < E0)           { tau = w - 1; i = e; }
        else if (e < E0 + E1) { tau = w;     i = e - E0; }
        else                  { tau = w + 1; i = e - E0 - E1; }

        const float wv = writhe_ij(cs, i, tau);
        const float pp = (wv + 1.0f) * INV_STEP;    // pp - k = (wv - c_k)/STEP
        const int k0 = __float2int_rn(pp);
        const int kmn = max(0, k0 - WIN);
        const int kmx = min(BINS - 1, k0 + WIN);
        const int klo = k0 - WIN;

        // deposit A: tau=w-1 -> node w, a=i+1; tau=w -> node w, a=i;
        //            tau=w+1 -> node w+1, a=i.  (all atoms already LDS-hot)
        const int nodeA = (tau == w + 1) ? 1 : 0;
        const int aA = (tau == w - 1) ? i + 1 : i;
        const float gA = gw(cs, aA, w + nodeA);
        // deposit B: only for the shared family tau==w -> node w+1, a=i+1
        const bool hasB = (tau == w);
        const float gB = hasB ? gw(cs, i + 1, w + 1) : 0.0f;

        if (nodeA == 0) { d0 += gA; kn0 = min(kn0, kmn); kx0 = max(kx0, kmx); }
        else            { d1 += gA; kn1 = min(kn1, kmn); kx1 = max(kx1, kmx); }
        if (hasB)       { d1 += gB; kn1 = min(kn1, kmn); kx1 = max(kx1, kmx); }

        const int bA = (nodeA ? baseB : baseA0);
        #pragma unroll
        for (int m = 0; m < WINW; ++m) {
            int mm = m + rot; if (mm >= WINW) mm -= WINW;
            const int k = klo + mm;
            if (k >= 0 && k < BINS) {
                const float dd = pp - (float)k;
                const float ww = __expf(-dd * dd);  // shared between A and B
                atomicAdd(&h2[bA + k], gA * ww);
                if (hasB) atomicAdd(&h2[baseB + k], gB * ww);
            }
        }
    }

    // per-wave masked butterflies for both nodes, one LDS atomic set per wave
    #pragma unroll
    for (int off = 32; off > 0; off >>= 1) {
        d0 += __shfl_xor(d0, off, 64);
        d1 += __shfl_xor(d1, off, 64);
        kn0 = min(kn0, __shfl_xor(kn0, off, 64));
        kx0 = max(kx0, __shfl_xor(kx0, off, 64));
        kn1 = min(kn1, __shfl_xor(kn1, off, 64));
        kx1 = max(kx1, __shfl_xor(kx1, off, 64));
    }
    if ((tid & 63) == 0) {
        atomicAdd(&sden[0], d0);
        atomicAdd(&sden[1], d1);
        atomicMin(&skmin[0], kn0);
        atomicMax(&skmax[0], kx0);
        atomicMin(&skmin[1], kn1);
        atomicMax(&skmax[1], kx1);
    }
    __syncthreads();

    // combine the 8 privatized copies per node into copy 0, touched range only
    {
        const int nu = tid >> 8;                    // 256 threads per node
        const int kmin = skmin[nu], kmax = skmax[nu];
        const int base = nu * NHIST * BINS;
        for (int k = kmin + (tid & 255); k <= kmax; k += 256) {
            float s = h2[base + k];
            #pragma unroll
            for (int c = 1; c < NHIST; ++c) s += h2[base + c * BINS + k];
            h2[base + k] = s;
        }
    }
    __syncthreads();

    // projection: 2 nodes x 2 bin-halves x 128 features (all 512 threads)
    {
        const int nu = tid >> 8;
        const int h = (tid >> 7) & 1;
        const int f = tid & 127;
        const int kmin = skmin[nu], kmax = skmax[nu];
        const int len = kmax - kmin + 1;
        const int half = (len + 1) >> 1;
        const int ks = kmin + h * half;
        const int ke = min(kmax + 1, ks + half);
        const int base = nu * NHIST * BINS;
        float acc = 0.0f;
        for (int k = ks; k < ke; ++k)
            acc = fmaf(h2[base + k], basis[k * N_FEAT + f], acc);
        part[((nu << 1) | h) * N_FEAT + f] = acc;
    }
    __syncthreads();

    if (tid < 256) {
        const int nu = tid >> 7;
        const int f = tid & 127;
        const int row = w + nu;
        const float scale = INV_112 / sden[nu];
        const float s = part[(nu << 1) * N_FEAT + f] + part[((nu << 1) | 1) * N_FEAT + f];
        out[((size_t)((b << 8) | row)) * N_FEAT + f] = mynf + s * scale;
    } else if (p == 0) {
        // passthrough rows t = 0, 1 (no incoming edges), from the (2,3) block
        const int tid2 = tid - 256;
        const int r = tid2 >> 7;
        const int f = tid2 & 127;
        const size_t idx = ((size_t)((b << 8) | r)) * N_FEAT + f;
        out[idx] = nf[idx];
    }
}

extern "C" void kernel_launch(void* const* d_in, const int* in_sizes, int n_in,
                              void* d_out, int out_size, void* d_ws, size_t ws_size,
                              hipStream_t stream) {
    const float* coords = (const float*)d_in[0];   // (B*N, 3) f32
    const float* nf     = (const float*)d_in[1];   // (B*N, 128) f32
    const float* basis  = (const float*)d_in[2];   // (300, 128) f32
    float* out = (float*)d_out;                    // (B*N, 128) f32

    fused_kernel<<<BATCH * 127, 512, 0, stream>>>(coords, nf, basis, out);
}

// Round 13
// 103.226 us; speedup vs baseline: 1.1733x; 1.1442x over previous
//
#include <hip/hip_runtime.h>
#include <math.h>

// Problem constants (match reference)
#define N_ATOMS 256
#define N_FEAT  128
#define BATCH   8
#define BINS    300
#define INV_STEP 149.5f        // 1/STEP, STEP = 2/(BINS-1)
#define ONE_OVER_2PI 0.15915494309189535f
#define INV_112 0.8928571428571429f   // 1/1.12
#define WIN 2                  // bins beyond |d|=2 contribute < exp(-9)*|basis| ~ 1e-5 << tol
#define WINW 5                 // 2*WIN+1
#define NHIST 8                // privatized histogram copies per node

struct V3 { float x, y, z; };
__device__ __forceinline__ V3 v3sub(V3 a, V3 b) { return {a.x-b.x, a.y-b.y, a.z-b.z}; }
__device__ __forceinline__ float v3dot(V3 a, V3 b) { return a.x*b.x + a.y*b.y + a.z*b.z; }
__device__ __forceinline__ V3 v3cross(V3 a, V3 b) {
    return {a.y*b.z - a.z*b.y, a.z*b.x - a.x*b.z, a.x*b.y - a.y*b.x};
}
__device__ __forceinline__ V3 v3nrm(V3 a) {
    float r = __builtin_amdgcn_rsqf(v3dot(a, a));   // v_rsq_f32
    return {a.x*r, a.y*r, a.z*r};
}
__device__ __forceinline__ float clamp1(float x) { return fminf(1.0f, fmaxf(-1.0f, x)); }

// Branchless Cephes asinf: |x|<=0.5 poly; else pi/2 - 2*asin(sqrt((1-|x|)/2)).
__device__ __forceinline__ float asin_fast(float x) {
    float u = fabsf(x);
    bool big = u > 0.5f;
    float z = big ? 0.5f * (1.0f - u) : u * u;
    float s = big ? __builtin_amdgcn_sqrtf(z) : u;  // v_sqrt_f32
    float p = fmaf(z, 4.2163199048e-2f, 2.4181311049e-2f);
    p = fmaf(z, p, 4.5470025998e-2f);
    p = fmaf(z, p, 7.4953002686e-2f);
    p = fmaf(z, p, 1.6666752422e-1f);
    float r = fmaf(s * z, p, s);
    r = big ? (1.5707963267948966f - 2.0f * r) : r;
    return copysignf(r, x);
}

// writhe of segment pair (i,i+1),(j,j+1) from float4-padded LDS coords
// (each point = one ds_read_b128, consecutive lanes -> consecutive addresses)
__device__ __forceinline__ float writhe_ij(const float4* cs, int i, int j) {
    const float4 qi  = cs[i],   qi1 = cs[i + 1];
    const float4 qj  = cs[j],   qj1 = cs[j + 1];
    V3 pi  = {qi.x,  qi.y,  qi.z};
    V3 pi1 = {qi1.x, qi1.y, qi1.z};
    V3 pj  = {qj.x,  qj.y,  qj.z};
    V3 pj1 = {qj1.x, qj1.y, qj1.z};

    V3 d0 = v3nrm(v3sub(pj,  pi));
    V3 d1 = v3nrm(v3sub(pj1, pi));
    V3 d2 = v3nrm(v3sub(pj,  pi1));
    V3 d3 = v3nrm(v3sub(pj1, pi1));

    V3 c0 = v3nrm(v3cross(d0, d1));
    V3 c1 = v3nrm(v3cross(d1, d3));
    V3 c2 = v3nrm(v3cross(d3, d2));
    V3 c3 = v3nrm(v3cross(d2, d0));

    float omega = asin_fast(clamp1(v3dot(c0, c1)))
                + asin_fast(clamp1(v3dot(c1, c2)))
                + asin_fast(clamp1(v3dot(c2, c3)))
                + asin_fast(clamp1(v3dot(c3, c0)));

    float sg = v3dot(v3cross(v3sub(pj1, pj), v3sub(pi1, pi)), d0);
    float sign = (sg > 0.0f) ? 1.0f : ((sg < 0.0f) ? -1.0f : 0.0f);
    return omega * sign * ONE_OVER_2PI;
}

// One 512-thread block per NODE PAIR (t0, t1) = (p+2, 255-p), same batch.
// Edge counts sum to 508 for p>=1 (254 for p=0): one edge per thread.
// Node tau edges: type-1 = segment (a,tau), a in [0,tau-2] (iff tau<=254);
// type-2 = segment (a-1,tau-1), a in [1,tau-2]; weight g = exp(-|c_a-c_tau|^2).
__global__ __launch_bounds__(512) void fused_kernel(const float* __restrict__ coords,
                                                    const float* __restrict__ nf,
                                                    const float* __restrict__ basis,
                                                    float* __restrict__ out) {
    const int blk = blockIdx.x;
    const int b = blk & 7;
    const int p = blk >> 3;            // pair index 0..126
    const int t0 = p + 2;              // 2..128
    const int t1 = 255 - p;            // 255..129
    const int tid = threadIdx.x;

    const int E0  = 2 * t0 - 3;                         // edges of node t0 (>=1)
    const int E1n = (t1 == 255) ? 253 : 2 * t1 - 3;     // edges of node t1

    float mynf = 0.0f;
    if (tid < 256) {                   // prefetch nf rows t0 (tid<128) and t1
        const int row = (tid >> 7) ? t1 : t0;
        mynf = nf[((size_t)((b << 8) | row)) * N_FEAT + (tid & 127)];
    }

    __shared__ float4 cs[N_ATOMS];           // 4 KB, padded xyz0
    __shared__ float h2[2 * NHIST * BINS];   // 19.2 KB (two 8-copy histograms)
    __shared__ float part[4 * N_FEAT];       // 2 KB
    __shared__ float sden[2];
    __shared__ int skmin[2], skmax[2];

    if (tid < N_ATOMS) {
        const int gbase = ((b << 8) + tid) * 3;
        cs[tid] = make_float4(coords[gbase], coords[gbase + 1], coords[gbase + 2], 0.0f);
    }
    for (int k = tid; k < 2 * NHIST * BINS; k += 512) h2[k] = 0.0f;
    if (tid < 2) { sden[tid] = 0.0f; skmin[tid] = BINS - 1; skmax[tid] = 0; }
    __syncthreads();

    int node = -1;
    int tau = t0;
    if (tid < E0) { node = 0; tau = t0; }
    else if (tid < E0 + E1n) { node = 1; tau = t1; }
    const int ee = (node == 1) ? tid - E0 : tid;

    float d0 = 0.0f, d1 = 0.0f;
    int kn0 = BINS - 1, kx0 = 0, kn1 = BINS - 1, kx1 = 0;

    if (node >= 0) {
        const int eT1 = (tau <= N_ATOMS - 2) ? tau - 1 : 0;
        const int typ = (ee < eT1) ? 0 : 1;
        const int a = (typ == 0) ? ee : ee - eT1 + 1;

        const float4 qa = cs[a];
        const float4 qt = cs[tau];
        float dx = qa.x - qt.x;
        float dy = qa.y - qt.y;
        float dz = qa.z - qt.z;
        float g = __expf(-(dx*dx + dy*dy + dz*dz));

        float w = (typ == 0) ? writhe_ij(cs, a, tau) : writhe_ij(cs, a - 1, tau - 1);
        float pp = (w + 1.0f) * INV_STEP;    // pp - k = (w - c_k)/STEP
        int k0 = __float2int_rn(pp);
        int kmn = max(0, k0 - WIN);
        int kmx = min(BINS - 1, k0 + WIN);
        if (node == 0) { d0 = g; kn0 = kmn; kx0 = kmx; }
        else           { d1 = g; kn1 = kmn; kx1 = kmx; }

        const int copy = tid & (NHIST - 1);
        const int rot = tid % WINW;          // (tid&7, tid%5): <=2-way alias in a wave (free)
        const int base = (node * NHIST + copy) * BINS;
        const int klo = k0 - WIN;
        #pragma unroll
        for (int m = 0; m < WINW; ++m) {
            int mm = m + rot; if (mm >= WINW) mm -= WINW;
            int k = klo + mm;
            if (k >= 0 && k < BINS) {
                float dd = pp - (float)k;
                atomicAdd(&h2[base + k], g * __expf(-dd * dd));
            }
        }
    }

    // per-wave masked butterflies for both nodes, one LDS atomic set per wave
    #pragma unroll
    for (int off = 32; off > 0; off >>= 1) {
        d0 += __shfl_xor(d0, off, 64);
        d1 += __shfl_xor(d1, off, 64);
        kn0 = min(kn0, __shfl_xor(kn0, off, 64));
        kx0 = max(kx0, __shfl_xor(kx0, off, 64));
        kn1 = min(kn1, __shfl_xor(kn1, off, 64));
        kx1 = max(kx1, __shfl_xor(kx1, off, 64));
    }
    if ((tid & 63) == 0) {
        atomicAdd(&sden[0], d0);
        atomicAdd(&sden[1], d1);
        atomicMin(&skmin[0], kn0);
        atomicMax(&skmax[0], kx0);
        atomicMin(&skmin[1], kn1);
        atomicMax(&skmax[1], kx1);
    }
    __syncthreads();

    // combine the 8 privatized copies per node, over touched range only
    {
        const int nu = tid >> 8;             // 256 threads per node
        const int kmin = skmin[nu], kmax = skmax[nu];
        const int base = nu * NHIST * BINS;
        for (int k = kmin + (tid & 255); k <= kmax; k += 256) {
            float s = h2[base + k];
            #pragma unroll
            for (int c = 1; c < NHIST; ++c) s += h2[base + c * BINS + k];
            h2[base + k] = s;
        }
    }
    __syncthreads();

    // projection: 2 nodes x 2 bin-halves x 128 features
    {
        const int nu = tid >> 8;
        const int h = (tid >> 7) & 1;
        const int f = tid & 127;
        const int kmin = skmin[nu], kmax = skmax[nu];
        const int len = kmax - kmin + 1;
        const int half = (len + 1) >> 1;
        const int ks = kmin + h * half;
        const int ke = min(kmax + 1, ks + half);
        const int base = nu * NHIST * BINS;
        float acc = 0.0f;
        for (int k = ks; k < ke; ++k)
            acc = fmaf(h2[base + k], basis[k * N_FEAT + f], acc);
        part[((nu << 1) | h) * N_FEAT + f] = acc;
    }
    __syncthreads();

    if (tid < 256) {
        const int nu = tid >> 7;
        const int f = tid & 127;
        const int row = nu ? t1 : t0;
        const float scale = INV_112 / sden[nu];
        const float s = part[(nu << 1) * N_FEAT + f] + part[((nu << 1) | 1) * N_FEAT + f];
        out[((size_t)((b << 8) | row)) * N_FEAT + f] = mynf + s * scale;
    } else if (p == 0) {
        // passthrough rows t = 0, 1 (no incoming edges), handled by the (2,255) block
        const int tid2 = tid - 256;
        const int r = tid2 >> 7;
        const int f = tid2 & 127;
        const size_t idx = ((size_t)((b << 8) | r)) * N_FEAT + f;
        out[idx] = nf[idx];
    }
}

extern "C" void kernel_launch(void* const* d_in, const int* in_sizes, int n_in,
                              void* d_out, int out_size, void* d_ws, size_t ws_size,
                              hipStream_t stream) {
    const float* coords = (const float*)d_in[0];   // (B*N, 3) f32
    const float* nf     = (const float*)d_in[1];   // (B*N, 128) f32
    const float* basis  = (const float*)d_in[2];   // (300, 128) f32
    float* out = (float*)d_out;                    // (B*N, 128) f32

    fused_kernel<<<BATCH * 127, 512, 0, stream>>>(coords, nf, basis, out);
}